// Round 1
// baseline (233.852 us; speedup 1.0000x reference)
//
#include <hip/hip_runtime.h>
#include <stdint.h>

typedef __attribute__((ext_vector_type(8))) short s16x8;
typedef __attribute__((ext_vector_type(4))) float f32x4;

__device__ __forceinline__ unsigned short f32_bf16(float f) {
  union { float f; uint32_t u; } v; v.f = f;
  return (unsigned short)((v.u + 0x7FFFu + ((v.u >> 16) & 1u)) >> 16);
}

// ---------------- kernel 1: weight f32 -> bf16 ----------------
__global__ void convert_w(const float* __restrict__ wqkv,
                          const float* __restrict__ wout,
                          unsigned short* __restrict__ o) {
  int i = blockIdx.x * 256 + threadIdx.x;           // 262144 total
  if (i < 768 * 256) o[i] = f32_bf16(wqkv[i]);
  else               o[i] = f32_bf16(wout[i - 768 * 256]);
}

// ---------------- kernel 2: fused QKV + attention per 64-token group ----
// block = 512 threads (8 waves), wave w handles head w.
// LDS: x tile 32KB (swizzled) + per-wave 12KB {q,k -> reused as P; v^T}
__global__ __launch_bounds__(512) void qkv_attn(
    const float* __restrict__ x,
    const unsigned short* __restrict__ wqkv,   // [768][256] bf16
    unsigned short* __restrict__ aout) {       // [N][256] bf16
  __shared__ unsigned short xt[64 * 256];      // 32 KB
  __shared__ unsigned short wb[8][6144];       // 96 KB

  const int g    = blockIdx.x;
  const int tid  = threadIdx.x;
  const int w    = tid >> 6;
  const int lane = tid & 63;
  const int l15  = lane & 15;
  const int l4   = lane >> 4;

  // ---- stage x (64x256 f32 -> bf16, XOR swizzled rows) ----
  {
    const int row = tid >> 3;
    const int c0  = (tid & 7) * 32;
    const float* src = x + (size_t)(g * 64 + row) * 256 + c0;
#pragma unroll
    for (int c = 0; c < 32; c += 8) {
      float4 f0 = *(const float4*)(src + c);
      float4 f1 = *(const float4*)(src + c + 4);
      uint32_t p0 = f32_bf16(f0.x) | ((uint32_t)f32_bf16(f0.y) << 16);
      uint32_t p1 = f32_bf16(f0.z) | ((uint32_t)f32_bf16(f0.w) << 16);
      uint32_t p2 = f32_bf16(f1.x) | ((uint32_t)f32_bf16(f1.y) << 16);
      uint32_t p3 = f32_bf16(f1.z) | ((uint32_t)f32_bf16(f1.w) << 16);
      uint32_t byte = (uint32_t)(row * 512 + (c0 + c) * 2);
      byte ^= (row & 7) << 4;
      *(uint4*)((char*)xt + byte) = make_uint4(p0, p1, p2, p3);
    }
  }
  __syncthreads();

  // ---- QKV: acc[t] t=0,1:q cols {0,16}; 2,3:k; 4,5:v (per-head 32 cols) ----
  f32x4 acc[6][4];
#pragma unroll
  for (int t = 0; t < 6; ++t)
#pragma unroll
    for (int m = 0; m < 4; ++m) acc[t][m] = (f32x4){0.f, 0.f, 0.f, 0.f};

  for (int kk = 0; kk < 8; ++kk) {
    s16x8 a[4];
#pragma unroll
    for (int m = 0; m < 4; ++m) {
      int row = 16 * m + l15;
      uint32_t byte = (uint32_t)(row * 512 + kk * 64 + l4 * 16) ^ ((row & 7) << 4);
      a[m] = *(const s16x8*)((const char*)xt + byte);
    }
#pragma unroll
    for (int t = 0; t < 6; ++t) {
      int wrow = (t >> 1) * 256 + w * 32 + (t & 1) * 16 + l15;
      s16x8 b = *(const s16x8*)(wqkv + (size_t)wrow * 256 + kk * 32 + l4 * 8);
#pragma unroll
      for (int m = 0; m < 4; ++m)
        acc[t][m] = __builtin_amdgcn_mfma_f32_16x16x32_bf16(a[m], b, acc[t][m], 0, 0, 0);
    }
  }

  unsigned short* q_l = wb[w];            // [64][32] bf16 (swz rows, 64B)
  unsigned short* k_l = wb[w] + 2048;     // [64][32]
  unsigned short* vt  = wb[w] + 4096;     // [32][64]  (V transposed)

  // write q,k from C-layout (row = 16m + 4*l4 + r, col = 16*(t&1) + l15)
#pragma unroll
  for (int t = 0; t < 4; ++t) {
    unsigned short* dst = (t < 2) ? q_l : k_l;
    int col = (t & 1) * 16 + l15;
#pragma unroll
    for (int m = 0; m < 4; ++m) {
#pragma unroll
      for (int r = 0; r < 4; ++r) {
        int row = 16 * m + l4 * 4 + r;
        uint32_t byte = (uint32_t)(row * 64 + col * 2) ^ ((row & 3) << 4);
        *(unsigned short*)((char*)dst + byte) = f32_bf16(acc[t][m][r]);
      }
    }
  }
  // write v^T: vt[d][token], 4 consecutive tokens packed per 8B write
#pragma unroll
  for (int t = 4; t < 6; ++t) {
    int d = (t - 4) * 16 + l15;
#pragma unroll
    for (int m = 0; m < 4; ++m) {
      uint32_t p0 = f32_bf16(acc[t][m][0]) | ((uint32_t)f32_bf16(acc[t][m][1]) << 16);
      uint32_t p1 = f32_bf16(acc[t][m][2]) | ((uint32_t)f32_bf16(acc[t][m][3]) << 16);
      uint32_t byte = (uint32_t)(d * 128 + m * 32 + l4 * 8) ^ ((d & 7) << 4);
      *(uint2*)((char*)vt + byte) = make_uint2(p0, p1);
    }
  }

  // ---- energy = q k^T (64x64), single K-step (HD=32) ----
  f32x4 e[4][4];
#pragma unroll
  for (int m = 0; m < 4; ++m)
#pragma unroll
    for (int n = 0; n < 4; ++n) e[m][n] = (f32x4){0.f, 0.f, 0.f, 0.f};

  {
    s16x8 qa[4], kb[4];
#pragma unroll
    for (int m = 0; m < 4; ++m) {
      int row = 16 * m + l15;
      uint32_t byte = (uint32_t)(row * 64 + l4 * 16) ^ ((row & 3) << 4);
      qa[m] = *(const s16x8*)((const char*)q_l + byte);
      kb[m] = *(const s16x8*)((const char*)k_l + byte);
    }
#pragma unroll
    for (int m = 0; m < 4; ++m)
#pragma unroll
      for (int n = 0; n < 4; ++n)
        e[m][n] = __builtin_amdgcn_mfma_f32_16x16x32_bf16(qa[m], kb[n], e[m][n], 0, 0, 0);
  }

  // ---- softmax over keys (cols): lane-local over n, shfl over 16-lane group
  const float s = 0.0625f;  // 1/sqrt(256)
  unsigned short* P = wb[w];  // [64][64] bf16, reuses q/k space
#pragma unroll
  for (int m = 0; m < 4; ++m) {
#pragma unroll
    for (int r = 0; r < 4; ++r) {
      float mx = fmaxf(fmaxf(e[m][0][r], e[m][1][r]), fmaxf(e[m][2][r], e[m][3][r]));
#pragma unroll
      for (int d = 1; d < 16; d <<= 1) mx = fmaxf(mx, __shfl_xor(mx, d));
      float p0 = __expf((e[m][0][r] - mx) * s);
      float p1 = __expf((e[m][1][r] - mx) * s);
      float p2 = __expf((e[m][2][r] - mx) * s);
      float p3 = __expf((e[m][3][r] - mx) * s);
      float sum = p0 + p1 + p2 + p3;
#pragma unroll
      for (int d = 1; d < 16; d <<= 1) sum += __shfl_xor(sum, d);
      float rs = 1.0f / sum;
      int row = 16 * m + l4 * 4 + r;
      uint32_t rb = (uint32_t)(row * 128);
      uint32_t sw = (row & 7) << 4;
      *(unsigned short*)((char*)P + ((rb + (uint32_t)(l15 * 2))        ^ sw)) = f32_bf16(p0 * rs);
      *(unsigned short*)((char*)P + ((rb + (uint32_t)((16 + l15) * 2)) ^ sw)) = f32_bf16(p1 * rs);
      *(unsigned short*)((char*)P + ((rb + (uint32_t)((32 + l15) * 2)) ^ sw)) = f32_bf16(p2 * rs);
      *(unsigned short*)((char*)P + ((rb + (uint32_t)((48 + l15) * 2)) ^ sw)) = f32_bf16(p3 * rs);
    }
  }

  // ---- out = P @ V  (64x32), K=64 in 2 steps ----
  f32x4 o[4][2];
#pragma unroll
  for (int m = 0; m < 4; ++m) { o[m][0] = (f32x4){0.f,0.f,0.f,0.f}; o[m][1] = (f32x4){0.f,0.f,0.f,0.f}; }
#pragma unroll
  for (int kk2 = 0; kk2 < 2; ++kk2) {
    s16x8 pa[4], vb[2];
#pragma unroll
    for (int m = 0; m < 4; ++m) {
      int row = 16 * m + l15;
      uint32_t byte = (uint32_t)(row * 128 + kk2 * 64 + l4 * 16) ^ ((row & 7) << 4);
      pa[m] = *(const s16x8*)((const char*)P + byte);
    }
#pragma unroll
    for (int n = 0; n < 2; ++n) {
      int d = 16 * n + l15;
      uint32_t byte = (uint32_t)(d * 128 + kk2 * 64 + l4 * 16) ^ ((d & 7) << 4);
      vb[n] = *(const s16x8*)((const char*)vt + byte);
    }
#pragma unroll
    for (int m = 0; m < 4; ++m)
#pragma unroll
      for (int n = 0; n < 2; ++n)
        o[m][n] = __builtin_amdgcn_mfma_f32_16x16x32_bf16(pa[m], vb[n], o[m][n], 0, 0, 0);
  }

  // ---- store attn output (bf16) at [g*64+tok][w*32 + d] ----
  unsigned short* dstbase = aout + (size_t)g * 64 * 256 + w * 32;
#pragma unroll
  for (int m = 0; m < 4; ++m)
#pragma unroll
    for (int n = 0; n < 2; ++n)
#pragma unroll
      for (int r = 0; r < 4; ++r) {
        int tok = 16 * m + l4 * 4 + r;
        dstbase[(size_t)tok * 256 + 16 * n + l15] = f32_bf16(o[m][n][r]);
      }
}

// ---------------- kernel 3: out = attn @ w_out^T + b ----------------
// 128x128 tile, 4 waves (2x2), BK=64, swizzled reg-staged LDS
__global__ __launch_bounds__(256) void proj(
    const unsigned short* __restrict__ A,    // [131072][256] bf16
    const unsigned short* __restrict__ Bw,   // [256][256] bf16
    const float* __restrict__ bias,
    float* __restrict__ out) {
  __shared__ unsigned short As[128 * 64];
  __shared__ unsigned short Bs[128 * 64];
  const int bm = blockIdx.x, bn = blockIdx.y;
  const int tid = threadIdx.x;
  const int w = tid >> 6, lane = tid & 63;
  const int l15 = lane & 15, l4 = lane >> 4;
  const int wr = w >> 1, wc = w & 1;

  f32x4 acc[4][4];
#pragma unroll
  for (int mi = 0; mi < 4; ++mi)
#pragma unroll
    for (int ni = 0; ni < 4; ++ni) acc[mi][ni] = (f32x4){0.f, 0.f, 0.f, 0.f};

  const int srow = tid >> 1;
  const int sc0  = (tid & 1) * 32;
  const unsigned short* ga = A  + (size_t)(bm * 128 + srow) * 256 + sc0;
  const unsigned short* gb = Bw + (size_t)(bn * 128 + srow) * 256 + sc0;

  for (int kk = 0; kk < 4; ++kk) {
#pragma unroll
    for (int c = 0; c < 32; c += 8) {
      uint4 va = *(const uint4*)(ga + kk * 64 + c);
      uint4 vb = *(const uint4*)(gb + kk * 64 + c);
      uint32_t byte = (uint32_t)(srow * 128 + (sc0 + c) * 2) ^ ((srow & 7) << 4);
      *(uint4*)((char*)As + byte) = va;
      *(uint4*)((char*)Bs + byte) = vb;
    }
    __syncthreads();
#pragma unroll
    for (int k2 = 0; k2 < 2; ++k2) {
      s16x8 af[4], bf[4];
#pragma unroll
      for (int mi = 0; mi < 4; ++mi) {
        int row = wr * 64 + 16 * mi + l15;
        uint32_t byte = (uint32_t)(row * 128 + k2 * 64 + l4 * 16) ^ ((row & 7) << 4);
        af[mi] = *(const s16x8*)((const char*)As + byte);
      }
#pragma unroll
      for (int ni = 0; ni < 4; ++ni) {
        int row = wc * 64 + 16 * ni + l15;
        uint32_t byte = (uint32_t)(row * 128 + k2 * 64 + l4 * 16) ^ ((row & 7) << 4);
        bf[ni] = *(const s16x8*)((const char*)Bs + byte);
      }
#pragma unroll
      for (int mi = 0; mi < 4; ++mi)
#pragma unroll
        for (int ni = 0; ni < 4; ++ni)
          acc[mi][ni] = __builtin_amdgcn_mfma_f32_16x16x32_bf16(af[mi], bf[ni], acc[mi][ni], 0, 0, 0);
    }
    __syncthreads();
  }

#pragma unroll
  for (int mi = 0; mi < 4; ++mi)
#pragma unroll
    for (int ni = 0; ni < 4; ++ni) {
      int col = bn * 128 + wc * 64 + 16 * ni + l15;
      float b = bias[col];
#pragma unroll
      for (int r = 0; r < 4; ++r) {
        int row = bm * 128 + wr * 64 + 16 * mi + l4 * 4 + r;
        out[(size_t)row * 256 + col] = acc[mi][ni][r] + b;
      }
    }
}

extern "C" void kernel_launch(void* const* d_in, const int* in_sizes, int n_in,
                              void* d_out, int out_size, void* d_ws, size_t ws_size,
                              hipStream_t stream) {
  const float* x    = (const float*)d_in[0];
  const float* wqkv = (const float*)d_in[1];
  const float* wout = (const float*)d_in[2];
  const float* bout = (const float*)d_in[3];
  float* out = (float*)d_out;

  unsigned short* wq_bf = (unsigned short*)d_ws;          // 768*256 bf16
  unsigned short* wo_bf = wq_bf + 768 * 256;              // 256*256 bf16
  unsigned short* aout  = wo_bf + 256 * 256;              // 131072*256 bf16

  convert_w<<<1024, 256, 0, stream>>>(wqkv, wout, wq_bf);
  qkv_attn<<<2048, 512, 0, stream>>>(x, wq_bf, aout);
  proj<<<dim3(1024, 2), 256, 0, stream>>>(aout, wo_bf, bout, out);
}